// Round 2
// baseline (921.139 us; speedup 1.0000x reference)
//
#include <hip/hip_runtime.h>

// GRU: B=4096, T=512, I=32, H=64. One WG per 16-batch tile, 4 waves.
// Wave w owns hidden slice [w*16, w*16+16) for all 3 gates.
// GEMM orientation: hp^T = W_hh * h^T  (A = weight rows in registers,
// B = h^T from LDS, one b128 read per K-chunk, one b64 write per step).
//
// R1 change vs R0: (1) raw `s_waitcnt lgkmcnt(0); s_barrier` instead of
// __syncthreads() — __syncthreads' vmcnt(0) drain was putting the full
// global-load latency of the seq prefetch on every step's critical path
// (R0: 2088 cyc/step, MfmaUtil 7%). LDS visibility only needs lgkmcnt.
// (2) 4-deep register prefetch queue for seq (3 steps ahead ≈ >1200 cyc
// slack) so HBM-miss latency (~900 cyc) stays off the critical path.

#define TSTEPS 512
#define IDIM 32
#define HDIM 64
#define PF 4  // prefetch queue depth (power of 2, divides TSTEPS)

typedef __bf16 bf16x8 __attribute__((ext_vector_type(8)));
typedef __bf16 bf16x4 __attribute__((ext_vector_type(4)));
typedef float f32x4 __attribute__((ext_vector_type(4)));

__device__ __forceinline__ float fast_sigmoid(float x) {
    return __builtin_amdgcn_rcpf(1.0f + __expf(-x));
}
__device__ __forceinline__ float fast_tanh(float x) {
    // tanh(x) = 1 - 2/(1+e^{2x}); exp overflow -> inf -> rcp -> 0 (correct limit)
    return 1.0f - 2.0f * __builtin_amdgcn_rcpf(1.0f + __expf(2.0f * x));
}

// Workgroup barrier WITHOUT the vmcnt(0) drain __syncthreads emits.
// LDS producer->consumer across waves only needs lgkmcnt(0) + s_barrier;
// leaving vmem loads in flight keeps the seq prefetch off the critical path.
__device__ __forceinline__ void lds_barrier() {
    asm volatile("s_waitcnt lgkmcnt(0)\n\ts_barrier" ::: "memory");
}

__global__ __launch_bounds__(256) void gru_fused_kernel(
    const float* __restrict__ seq, const float* __restrict__ W_ih,
    const float* __restrict__ W_hh, const float* __restrict__ b_ih,
    const float* __restrict__ b_hh, float* __restrict__ out)
{
    // h^T in bf16, double-buffered. Row = batch (16), col = hidden k (64, pad to 72).
    // stride 144 B keeps 16 B alignment for b128 reads; 2-way bank aliasing is free.
    __shared__ __bf16 hB[2][16][72];

    const int tid  = threadIdx.x;
    const int w    = tid >> 6;        // wave id 0..3 -> hidden slice
    const int lane = tid & 63;
    const int l    = lane & 15;       // batch col within tile / A row within 16-tile
    const int q    = lane >> 4;       // quad -> k offset q*8
    const int b0   = blockIdx.x * 16;

    // zero-init h (t=0 reads buffer 0; init both)
    for (int i = tid; i < 2 * 16 * 72; i += 256)
        (&hB[0][0][0])[i] = (__bf16)0.0f;

    // ---- loop-invariant A-fragments (weights), bf16 ----
    // A[m][k]: m = lane&15 -> gate row g*64 + w*16 + l ; k = kc*32 + q*8 + j
    bf16x8 aH[3][2];  // [gate r/z/n][k-chunk]
    bf16x8 aI[3];     // input weights, K=32 (one chunk)
    #pragma unroll
    for (int g = 0; g < 3; ++g) {
        const int row = g * 64 + w * 16 + l;
        #pragma unroll
        for (int kc = 0; kc < 2; ++kc) {
            const float* p = W_hh + row * HDIM + kc * 32 + q * 8;
            #pragma unroll
            for (int j = 0; j < 8; ++j) aH[g][kc][j] = (__bf16)p[j];
        }
        const float* pi = W_ih + row * IDIM + q * 8;
        #pragma unroll
        for (int j = 0; j < 8; ++j) aI[g][j] = (__bf16)pi[j];
    }

    // ---- biases at this lane's C/D rows: hidden offset = w*16 + 4q + reg ----
    float biasR[4], biasZ[4], biasIN[4], biasHN[4];
    #pragma unroll
    for (int r = 0; r < 4; ++r) {
        const int g = w * 16 + 4 * q + r;
        biasR[r]  = b_ih[g]       + b_hh[g];
        biasZ[r]  = b_ih[64 + g]  + b_hh[64 + g];
        biasIN[r] = b_ih[128 + g];          // n-gate: keep separate, r scales hn only
        biasHN[r] = b_hh[128 + g];
    }

    float h[4] = {0.f, 0.f, 0.f, 0.f};  // fp32 h at this lane's C/D positions

    // seq row for B-operand of input proj: B[k][n] = seq[b0+l][t][k], k = q*8+j
    const float* seqRow = seq + ((size_t)(b0 + l) * TSTEPS) * IDIM + q * 8;

    // ---- 4-deep prefetch queue: slot t&3 consumed at step t, refilled with t+3 ----
    float4 q0[PF], q1[PF];
    #pragma unroll
    for (int s = 0; s < PF - 1; ++s) {
        const float* p = seqRow + (size_t)s * IDIM;
        q0[s] = *(const float4*)(p);
        q1[s] = *(const float4*)(p + 4);
    }

    __syncthreads();  // full barrier once (covers the zero-init)

    const f32x4 zero4 = {0.f, 0.f, 0.f, 0.f};

    #pragma unroll PF
    for (int t = 0; t < TSTEPS; ++t) {
        const int buf = t & 1;
        const int slot = t & (PF - 1);

        // issue long-latency LDS reads of h^T first (written last step; barrier ordered it)
        bf16x8 hb0 = *(const bf16x8*)&hB[buf][l][q * 8];
        bf16x8 hb1 = *(const bf16x8*)&hB[buf][l][32 + q * 8];

        // consume prefetched x while LDS reads are in flight
        float x[8];
        x[0] = q0[slot].x; x[1] = q0[slot].y; x[2] = q0[slot].z; x[3] = q0[slot].w;
        x[4] = q1[slot].x; x[5] = q1[slot].y; x[6] = q1[slot].z; x[7] = q1[slot].w;

        // refill slot with step t+PF-1 (clamped; tail re-reads step 511, harmless)
        {
            int tn = t + PF - 1; if (tn >= TSTEPS) tn = TSTEPS - 1;
            const float* pn = seqRow + (size_t)tn * IDIM;
            const int ns = tn & (PF - 1);
            q0[ns] = *(const float4*)(pn);
            q1[ns] = *(const float4*)(pn + 4);
        }

        bf16x8 xb;
        #pragma unroll
        for (int j = 0; j < 8; ++j) xb[j] = (__bf16)x[j];

        // x-proj MFMAs first: independent of h, overlap the ds_read latency
        f32x4 accR  = __builtin_amdgcn_mfma_f32_16x16x32_bf16(aI[0], xb, zero4, 0, 0, 0);
        f32x4 accZ  = __builtin_amdgcn_mfma_f32_16x16x32_bf16(aI[1], xb, zero4, 0, 0, 0);
        f32x4 accXN = __builtin_amdgcn_mfma_f32_16x16x32_bf16(aI[2], xb, zero4, 0, 0, 0);
        accR  = __builtin_amdgcn_mfma_f32_16x16x32_bf16(aH[0][0], hb0, accR, 0, 0, 0);
        accR  = __builtin_amdgcn_mfma_f32_16x16x32_bf16(aH[0][1], hb1, accR, 0, 0, 0);
        accZ  = __builtin_amdgcn_mfma_f32_16x16x32_bf16(aH[1][0], hb0, accZ, 0, 0, 0);
        accZ  = __builtin_amdgcn_mfma_f32_16x16x32_bf16(aH[1][1], hb1, accZ, 0, 0, 0);
        f32x4 accHN = __builtin_amdgcn_mfma_f32_16x16x32_bf16(aH[2][0], hb0, zero4, 0, 0, 0);
        accHN = __builtin_amdgcn_mfma_f32_16x16x32_bf16(aH[2][1], hb1, accHN, 0, 0, 0);

        bf16x4 hOut;
        #pragma unroll
        for (int r = 0; r < 4; ++r) {
            const float rg = fast_sigmoid(accR[r] + biasR[r]);
            const float zg = fast_sigmoid(accZ[r] + biasZ[r]);
            const float ng = fast_tanh(accXN[r] + biasIN[r] + rg * (accHN[r] + biasHN[r]));
            h[r] = ng + zg * (h[r] - ng);
            hOut[r] = (__bf16)h[r];
        }
        // 4 consecutive hidden indices (w*16+4q .. +3) for batch l -> one 8B write
        *(bf16x4*)&hB[buf ^ 1][l][w * 16 + 4 * q] = hOut;

        lds_barrier();  // lgkmcnt-only: vmem prefetch stays in flight
    }

    // out[b][k], k = w*16 + 4q + reg : 4 consecutive floats
    float4 o = {h[0], h[1], h[2], h[3]};
    *(float4*)&out[(size_t)(b0 + l) * HDIM + w * 16 + 4 * q] = o;
}

extern "C" void kernel_launch(void* const* d_in, const int* in_sizes, int n_in,
                              void* d_out, int out_size, void* d_ws, size_t ws_size,
                              hipStream_t stream) {
    const float* seq  = (const float*)d_in[0];
    const float* W_ih = (const float*)d_in[1];
    const float* W_hh = (const float*)d_in[2];
    const float* b_ih = (const float*)d_in[3];
    const float* b_hh = (const float*)d_in[4];
    float* out = (float*)d_out;
    // 4096 batches / 16 per WG = 256 workgroups (1 per CU)
    gru_fused_kernel<<<256, 256, 0, stream>>>(seq, W_ih, W_hh, b_ih, b_hh, out);
}

// Round 3
// 713.745 us; speedup vs baseline: 1.2906x; 1.2906x over previous
//
#include <hip/hip_runtime.h>

// GRU: B=4096, T=512, I=32, H=64. One WG per 16-batch tile, 4 waves.
// Wave w owns hidden slice [w*16, w*16+16) for all 3 gates.
// GEMM orientation: hp^T = W_hh * h^T  (A = weight rows in registers,
// B = h^T from LDS, one b128 read per K-chunk, one b64 write per step).
//
// R1 post-mortem: WRITE_SIZE 1->87 MB proved the PF queue spilled to
// scratch — the tail clamp made the refill slot index dynamic. R2 keeps
// the lgkmcnt-only barrier + 4-deep prefetch but clamps the ADDRESS only;
// with the t-loop fully unrolled by PF, all q0[]/q1[] indices fold to
// constants and the queue stays in VGPRs.

#define TSTEPS 512
#define IDIM 32
#define HDIM 64
#define PF 4  // prefetch queue depth (power of 2, divides TSTEPS)

typedef __bf16 bf16x8 __attribute__((ext_vector_type(8)));
typedef __bf16 bf16x4 __attribute__((ext_vector_type(4)));
typedef float f32x4 __attribute__((ext_vector_type(4)));

__device__ __forceinline__ float fast_sigmoid(float x) {
    return __builtin_amdgcn_rcpf(1.0f + __expf(-x));
}
__device__ __forceinline__ float fast_tanh(float x) {
    // tanh(x) = 1 - 2/(1+e^{2x}); exp overflow -> inf -> rcp -> 0 (correct limit)
    return 1.0f - 2.0f * __builtin_amdgcn_rcpf(1.0f + __expf(2.0f * x));
}

// Workgroup barrier WITHOUT the vmcnt(0) drain __syncthreads emits.
// LDS producer->consumer across waves only needs lgkmcnt(0) + s_barrier;
// leaving vmem loads in flight keeps the seq prefetch off the critical path.
__device__ __forceinline__ void lds_barrier() {
    asm volatile("s_waitcnt lgkmcnt(0)\n\ts_barrier" ::: "memory");
}

__global__ __launch_bounds__(256) void gru_fused_kernel(
    const float* __restrict__ seq, const float* __restrict__ W_ih,
    const float* __restrict__ W_hh, const float* __restrict__ b_ih,
    const float* __restrict__ b_hh, float* __restrict__ out)
{
    // h^T in bf16, double-buffered. Row = batch (16), col = hidden k (64, pad to 72).
    // stride 144 B keeps 16 B alignment for b128 reads.
    __shared__ __bf16 hB[2][16][72];

    const int tid  = threadIdx.x;
    const int w    = tid >> 6;        // wave id 0..3 -> hidden slice
    const int lane = tid & 63;
    const int l    = lane & 15;       // batch col within tile / A row within 16-tile
    const int q    = lane >> 4;       // quad -> k offset q*8
    const int b0   = blockIdx.x * 16;

    // zero-init h (t=0 reads buffer 0; init both)
    for (int i = tid; i < 2 * 16 * 72; i += 256)
        (&hB[0][0][0])[i] = (__bf16)0.0f;

    // ---- loop-invariant A-fragments (weights), bf16 ----
    // A[m][k]: m = lane&15 -> gate row g*64 + w*16 + l ; k = kc*32 + q*8 + j
    bf16x8 aH[3][2];  // [gate r/z/n][k-chunk]
    bf16x8 aI[3];     // input weights, K=32 (one chunk)
    #pragma unroll
    for (int g = 0; g < 3; ++g) {
        const int row = g * 64 + w * 16 + l;
        #pragma unroll
        for (int kc = 0; kc < 2; ++kc) {
            const float* p = W_hh + row * HDIM + kc * 32 + q * 8;
            #pragma unroll
            for (int j = 0; j < 8; ++j) aH[g][kc][j] = (__bf16)p[j];
        }
        const float* pi = W_ih + row * IDIM + q * 8;
        #pragma unroll
        for (int j = 0; j < 8; ++j) aI[g][j] = (__bf16)pi[j];
    }

    // ---- biases at this lane's C/D rows: hidden offset = w*16 + 4q + reg ----
    float biasR[4], biasZ[4], biasIN[4], biasHN[4];
    #pragma unroll
    for (int r = 0; r < 4; ++r) {
        const int g = w * 16 + 4 * q + r;
        biasR[r]  = b_ih[g]       + b_hh[g];
        biasZ[r]  = b_ih[64 + g]  + b_hh[64 + g];
        biasIN[r] = b_ih[128 + g];          // n-gate: keep separate, r scales hn only
        biasHN[r] = b_hh[128 + g];
    }

    float h[4] = {0.f, 0.f, 0.f, 0.f};  // fp32 h at this lane's C/D positions

    // seq row for B-operand of input proj: B[k][n] = seq[b0+l][t][k], k = q*8+j
    const float* seqRow = seq + ((size_t)(b0 + l) * TSTEPS) * IDIM + q * 8;

    // ---- 4-deep prefetch queue; ALL indices compile-time (loop unrolled by PF) ----
    float4 q0[PF], q1[PF];
    #pragma unroll
    for (int s = 0; s < PF - 1; ++s) {
        const float* p = seqRow + (size_t)s * IDIM;
        q0[s] = *(const float4*)(p);
        q1[s] = *(const float4*)(p + 4);
    }

    __syncthreads();  // full barrier once (covers the zero-init)

    const f32x4 zero4 = {0.f, 0.f, 0.f, 0.f};

    #pragma unroll PF
    for (int t = 0; t < TSTEPS; ++t) {
        const int buf = t & 1;
        const int slot = t & (PF - 1);          // static under unroll-PF

        // issue long-latency LDS reads of h^T first (written last step; barrier ordered it)
        bf16x8 hb0 = *(const bf16x8*)&hB[buf][l][q * 8];
        bf16x8 hb1 = *(const bf16x8*)&hB[buf][l][32 + q * 8];

        // consume prefetched x while LDS reads are in flight
        float x[8];
        x[0] = q0[slot].x; x[1] = q0[slot].y; x[2] = q0[slot].z; x[3] = q0[slot].w;
        x[4] = q1[slot].x; x[5] = q1[slot].y; x[6] = q1[slot].z; x[7] = q1[slot].w;

        // refill slot (t+PF-1); clamp the ADDRESS only — slot index stays static
        {
            const int tn = t + PF - 1;                      // NOT clamped -> ns folds
            const int ns = tn & (PF - 1);                   // static under unroll-PF
            const size_t toff = (size_t)(tn < TSTEPS ? tn : TSTEPS - 1) * IDIM;
            const float* pn = seqRow + toff;
            q0[ns] = *(const float4*)(pn);
            q1[ns] = *(const float4*)(pn + 4);
        }

        bf16x8 xb;
        #pragma unroll
        for (int j = 0; j < 8; ++j) xb[j] = (__bf16)x[j];

        // x-proj MFMAs first: independent of h, overlap the ds_read latency
        f32x4 accR  = __builtin_amdgcn_mfma_f32_16x16x32_bf16(aI[0], xb, zero4, 0, 0, 0);
        f32x4 accZ  = __builtin_amdgcn_mfma_f32_16x16x32_bf16(aI[1], xb, zero4, 0, 0, 0);
        f32x4 accXN = __builtin_amdgcn_mfma_f32_16x16x32_bf16(aI[2], xb, zero4, 0, 0, 0);
        accR  = __builtin_amdgcn_mfma_f32_16x16x32_bf16(aH[0][0], hb0, accR, 0, 0, 0);
        accR  = __builtin_amdgcn_mfma_f32_16x16x32_bf16(aH[0][1], hb1, accR, 0, 0, 0);
        accZ  = __builtin_amdgcn_mfma_f32_16x16x32_bf16(aH[1][0], hb0, accZ, 0, 0, 0);
        accZ  = __builtin_amdgcn_mfma_f32_16x16x32_bf16(aH[1][1], hb1, accZ, 0, 0, 0);
        f32x4 accHN = __builtin_amdgcn_mfma_f32_16x16x32_bf16(aH[2][0], hb0, zero4, 0, 0, 0);
        accHN = __builtin_amdgcn_mfma_f32_16x16x32_bf16(aH[2][1], hb1, accHN, 0, 0, 0);

        bf16x4 hOut;
        #pragma unroll
        for (int r = 0; r < 4; ++r) {
            const float rg = fast_sigmoid(accR[r] + biasR[r]);
            const float zg = fast_sigmoid(accZ[r] + biasZ[r]);
            const float ng = fast_tanh(accXN[r] + biasIN[r] + rg * (accHN[r] + biasHN[r]));
            h[r] = ng + zg * (h[r] - ng);
            hOut[r] = (__bf16)h[r];
        }
        // 4 consecutive hidden indices (w*16+4q .. +3) for batch l -> one 8B write
        *(bf16x4*)&hB[buf ^ 1][l][w * 16 + 4 * q] = hOut;

        lds_barrier();  // lgkmcnt-only: vmem prefetch stays in flight
    }

    // out[b][k], k = w*16 + 4q + reg : 4 consecutive floats
    float4 o = {h[0], h[1], h[2], h[3]};
    *(float4*)&out[(size_t)(b0 + l) * HDIM + w * 16 + 4 * q] = o;
}

extern "C" void kernel_launch(void* const* d_in, const int* in_sizes, int n_in,
                              void* d_out, int out_size, void* d_ws, size_t ws_size,
                              hipStream_t stream) {
    const float* seq  = (const float*)d_in[0];
    const float* W_ih = (const float*)d_in[1];
    const float* W_hh = (const float*)d_in[2];
    const float* b_ih = (const float*)d_in[3];
    const float* b_hh = (const float*)d_in[4];
    float* out = (float*)d_out;
    // 4096 batches / 16 per WG = 256 workgroups (1 per CU)
    gru_fused_kernel<<<256, 256, 0, stream>>>(seq, W_ih, W_hh, b_ih, b_hh, out);
}

// Round 4
// 689.671 us; speedup vs baseline: 1.3356x; 1.0349x over previous
//
#include <hip/hip_runtime.h>

// GRU: B=4096, T=512, I=32, H=64. One WG per 16-batch tile, 4 waves.
// Wave w owns hidden slice [w*16, w*16+16) for all 3 gates.
// hp^T = W_hh * h^T: A = weight rows in registers, B = h^T from LDS.
//
// R3 changes (critical-path shaving; structure unchanged):
//  - biases folded into MFMA C-inputs (accR/accZ/accXN/accHN start at bias)
//  - r,z weights+biases pre-scaled by -log2(e): sigmoid = rcp(1+exp2(y)),
//    no negate/scale on the critical path; tanh via exp2(2*log2e*v)
//  - x-proj MFMAs + bf16 cvt for step t+1 issued BEFORE the barrier
//    (h-independent; fills the barrier-arrival window), so the post-barrier
//    path is just ds_read -> 6 h-MFMAs -> activation -> ds_write.

#define TSTEPS 512
#define IDIM 32
#define HDIM 64
#define PF 4  // prefetch queue depth (power of 2)

typedef __bf16 bf16x8 __attribute__((ext_vector_type(8)));
typedef __bf16 bf16x4 __attribute__((ext_vector_type(4)));
typedef float f32x4 __attribute__((ext_vector_type(4)));

#define NLOG2E -1.4426950408889634f
#define TWOLOG2E 2.8853900817779268f

__device__ __forceinline__ void lds_barrier() {
    asm volatile("s_waitcnt lgkmcnt(0)\n\ts_barrier" ::: "memory");
}

__global__ __launch_bounds__(256) void gru_fused_kernel(
    const float* __restrict__ seq, const float* __restrict__ W_ih,
    const float* __restrict__ W_hh, const float* __restrict__ b_ih,
    const float* __restrict__ b_hh, float* __restrict__ out)
{
    __shared__ __bf16 hB[2][16][72];  // h^T double-buffered; 144 B row stride

    const int tid  = threadIdx.x;
    const int w    = tid >> 6;
    const int lane = tid & 63;
    const int l    = lane & 15;       // batch col
    const int q    = lane >> 4;       // quad
    const int b0   = blockIdx.x * 16;

    for (int i = tid; i < 2 * 16 * 72; i += 256)
        (&hB[0][0][0])[i] = (__bf16)0.0f;

    // ---- A-fragments; r,z gates pre-scaled by -log2e ----
    bf16x8 aH[3][2], aI[3];
    #pragma unroll
    for (int g = 0; g < 3; ++g) {
        const float scl = (g < 2) ? NLOG2E : 1.0f;
        const int row = g * 64 + w * 16 + l;
        #pragma unroll
        for (int kc = 0; kc < 2; ++kc) {
            const float* p = W_hh + row * HDIM + kc * 32 + q * 8;
            #pragma unroll
            for (int j = 0; j < 8; ++j) aH[g][kc][j] = (__bf16)(scl * p[j]);
        }
        const float* pi = W_ih + row * IDIM + q * 8;
        #pragma unroll
        for (int j = 0; j < 8; ++j) aI[g][j] = (__bf16)(scl * pi[j]);
    }

    // ---- bias C-init vectors at this lane's C/D rows (hidden = w*16+4q+r) ----
    f32x4 biasR4, biasZ4, biasXN4, biasHN4;
    #pragma unroll
    for (int r = 0; r < 4; ++r) {
        const int g = w * 16 + 4 * q + r;
        biasR4[r]  = NLOG2E * (b_ih[g]      + b_hh[g]);
        biasZ4[r]  = NLOG2E * (b_ih[64 + g] + b_hh[64 + g]);
        biasXN4[r] = b_ih[128 + g];
        biasHN4[r] = b_hh[128 + g];
    }

    float h[4] = {0.f, 0.f, 0.f, 0.f};

    const float* seqRow = seq + ((size_t)(b0 + l) * TSTEPS) * IDIM + q * 8;

    float4 q0[PF], q1[PF];
    #pragma unroll
    for (int s = 0; s < PF - 1; ++s) {
        const float* p = seqRow + (size_t)s * IDIM;
        q0[s] = *(const float4*)(p);
        q1[s] = *(const float4*)(p + 4);
    }

    __syncthreads();

    // ---- t=0 x-part (bias-init C) ----
    bf16x8 xb;
    #pragma unroll
    for (int j = 0; j < 4; ++j) { xb[j] = (__bf16)((const float*)&q0[0])[j];
                                  xb[4+j] = (__bf16)((const float*)&q1[0])[j]; }
    f32x4 accR  = __builtin_amdgcn_mfma_f32_16x16x32_bf16(aI[0], xb, biasR4, 0, 0, 0);
    f32x4 accZ  = __builtin_amdgcn_mfma_f32_16x16x32_bf16(aI[1], xb, biasZ4, 0, 0, 0);
    f32x4 accXN = __builtin_amdgcn_mfma_f32_16x16x32_bf16(aI[2], xb, biasXN4, 0, 0, 0);

    #pragma unroll PF
    for (int t = 0; t < TSTEPS; ++t) {
        const int buf = t & 1;

        // post-barrier critical path starts here
        bf16x8 hb0 = *(const bf16x8*)&hB[buf][l][q * 8];
        bf16x8 hb1 = *(const bf16x8*)&hB[buf][l][32 + q * 8];

        // refill prefetch slot (address-clamped; slot index static under unroll)
        {
            const int tn = t + PF - 1;
            const int ns = tn & (PF - 1);
            const size_t toff = (size_t)(tn < TSTEPS ? tn : TSTEPS - 1) * IDIM;
            const float* pn = seqRow + toff;
            q0[ns] = *(const float4*)(pn);
            q1[ns] = *(const float4*)(pn + 4);
        }

        accR = __builtin_amdgcn_mfma_f32_16x16x32_bf16(aH[0][0], hb0, accR, 0, 0, 0);
        accR = __builtin_amdgcn_mfma_f32_16x16x32_bf16(aH[0][1], hb1, accR, 0, 0, 0);
        accZ = __builtin_amdgcn_mfma_f32_16x16x32_bf16(aH[1][0], hb0, accZ, 0, 0, 0);
        accZ = __builtin_amdgcn_mfma_f32_16x16x32_bf16(aH[1][1], hb1, accZ, 0, 0, 0);
        f32x4 accHN = __builtin_amdgcn_mfma_f32_16x16x32_bf16(aH[2][0], hb0, biasHN4, 0, 0, 0);
        accHN = __builtin_amdgcn_mfma_f32_16x16x32_bf16(aH[2][1], hb1, accHN, 0, 0, 0);

        bf16x4 hOut;
        #pragma unroll
        for (int r = 0; r < 4; ++r) {
            // accR/accZ already = -log2e * (pre-activation incl. bias)
            const float rg = __builtin_amdgcn_rcpf(1.0f + __builtin_amdgcn_exp2f(accR[r]));
            const float zg = __builtin_amdgcn_rcpf(1.0f + __builtin_amdgcn_exp2f(accZ[r]));
            const float v  = accXN[r] + rg * accHN[r];
            const float u  = __builtin_amdgcn_exp2f(TWOLOG2E * v);
            const float ng = 1.0f - 2.0f * __builtin_amdgcn_rcpf(1.0f + u);
            h[r] = ng + zg * (h[r] - ng);
            hOut[r] = (__bf16)h[r];
        }
        *(bf16x4*)&hB[buf ^ 1][l][w * 16 + 4 * q] = hOut;

        // ---- pre-barrier work for t+1 (h-independent): cvt + x-proj MFMAs ----
        {
            const int s1 = (t + 1) & (PF - 1);   // static under unroll
            bf16x8 xb1;
            #pragma unroll
            for (int j = 0; j < 4; ++j) { xb1[j] = (__bf16)((const float*)&q0[s1])[j];
                                          xb1[4+j] = (__bf16)((const float*)&q1[s1])[j]; }
            accR  = __builtin_amdgcn_mfma_f32_16x16x32_bf16(aI[0], xb1, biasR4, 0, 0, 0);
            accZ  = __builtin_amdgcn_mfma_f32_16x16x32_bf16(aI[1], xb1, biasZ4, 0, 0, 0);
            accXN = __builtin_amdgcn_mfma_f32_16x16x32_bf16(aI[2], xb1, biasXN4, 0, 0, 0);
        }

        lds_barrier();
    }

    float4 o = {h[0], h[1], h[2], h[3]};
    *(float4*)&out[(size_t)(b0 + l) * HDIM + w * 16 + 4 * q] = o;
}

extern "C" void kernel_launch(void* const* d_in, const int* in_sizes, int n_in,
                              void* d_out, int out_size, void* d_ws, size_t ws_size,
                              hipStream_t stream) {
    const float* seq  = (const float*)d_in[0];
    const float* W_ih = (const float*)d_in[1];
    const float* W_hh = (const float*)d_in[2];
    const float* b_ih = (const float*)d_in[3];
    const float* b_hh = (const float*)d_in[4];
    float* out = (float*)d_out;
    gru_fused_kernel<<<256, 256, 0, stream>>>(seq, W_ih, W_hh, b_ih, b_hh, out);
}

// Round 5
// 582.566 us; speedup vs baseline: 1.5812x; 1.1839x over previous
//
#include <hip/hip_runtime.h>

// GRU: B=4096, T=512, I=32, H=64. One WG per 16-batch tile, 4 waves.
// Wave w owns hidden slice [w*16, w*16+16) for all 3 gates.
// hp^T = W_hh * h^T: A = weight rows in registers, B = h^T from LDS.
//
// R4: chunked burst seq loads. R2/R3 evidence: ANY per-step outstanding
// global load gets drained by the compiler-inserted s_waitcnt vmcnt(0)
// at the barrier (inline-asm "memory" barriers get the same conservative
// treatment as __syncthreads), costing ~400-500 cyc EVERY step. Fix:
// burst-load 8 timesteps at once into a register double-buffer at
// sub-steps 7/15 of a fully-unrolled 16-step inner loop (all queue
// indices compile-time). 7 of 8 barriers then have nothing outstanding
// (vmcnt(0) is free); one partial drain per 8 steps ~= 75 cyc/step.
// Plain __syncthreads() everywhere (safe; no asm tricks needed).
// __launch_bounds__(256,1): occupancy is structurally 1 wave/SIMD
// (256 batch-tiles x 4 waves = 1024 waves = exactly fills 256 CUs),
// so the ~220-VGPR register queue costs nothing.

#define TSTEPS 512
#define IDIM 32
#define HDIM 64

typedef __bf16 bf16x8 __attribute__((ext_vector_type(8)));
typedef __bf16 bf16x4 __attribute__((ext_vector_type(4)));
typedef float f32x4 __attribute__((ext_vector_type(4)));

#define NLOG2E -1.4426950408889634f
#define TWOLOG2E 2.8853900817779268f

__global__ __launch_bounds__(256, 1) void gru_fused_kernel(
    const float* __restrict__ seq, const float* __restrict__ W_ih,
    const float* __restrict__ W_hh, const float* __restrict__ b_ih,
    const float* __restrict__ b_hh, float* __restrict__ out)
{
    __shared__ __bf16 hB[2][16][72];  // h^T double-buffered; 144 B row stride

    const int tid  = threadIdx.x;
    const int w    = tid >> 6;
    const int lane = tid & 63;
    const int l    = lane & 15;       // batch col
    const int q    = lane >> 4;       // quad
    const int b0   = blockIdx.x * 16;

    for (int i = tid; i < 2 * 16 * 72; i += 256)
        (&hB[0][0][0])[i] = (__bf16)0.0f;

    // ---- A-fragments; r,z gates pre-scaled by -log2e ----
    bf16x8 aH[3][2], aI[3];
    #pragma unroll
    for (int g = 0; g < 3; ++g) {
        const float scl = (g < 2) ? NLOG2E : 1.0f;
        const int row = g * 64 + w * 16 + l;
        #pragma unroll
        for (int kc = 0; kc < 2; ++kc) {
            const float* p = W_hh + row * HDIM + kc * 32 + q * 8;
            #pragma unroll
            for (int j = 0; j < 8; ++j) aH[g][kc][j] = (__bf16)(scl * p[j]);
        }
        const float* pi = W_ih + row * IDIM + q * 8;
        #pragma unroll
        for (int j = 0; j < 8; ++j) aI[g][j] = (__bf16)(scl * pi[j]);
    }

    // ---- bias C-init vectors at this lane's C/D rows (hidden = w*16+4q+r) ----
    f32x4 biasR4, biasZ4, biasXN4, biasHN4;
    #pragma unroll
    for (int r = 0; r < 4; ++r) {
        const int g = w * 16 + 4 * q + r;
        biasR4[r]  = NLOG2E * (b_ih[g]      + b_hh[g]);
        biasZ4[r]  = NLOG2E * (b_ih[64 + g] + b_hh[64 + g]);
        biasXN4[r] = b_ih[128 + g];
        biasHN4[r] = b_hh[128 + g];
    }

    float h[4] = {0.f, 0.f, 0.f, 0.f};

    const float* seqRow = seq + ((size_t)(b0 + l) * TSTEPS) * IDIM + q * 8;

    // ---- 8-step double-buffered register queue: qA = even chunk, qB = odd ----
    float4 qA[8][2], qB[8][2];
    #pragma unroll
    for (int u = 0; u < 8; ++u) {
        const float* p = seqRow + (size_t)u * IDIM;
        qA[u][0] = *(const float4*)(p);
        qA[u][1] = *(const float4*)(p + 4);
    }
    #pragma unroll
    for (int u = 0; u < 8; ++u) {
        const float* p = seqRow + (size_t)(8 + u) * IDIM;
        qB[u][0] = *(const float4*)(p);
        qB[u][1] = *(const float4*)(p + 4);
    }

    __syncthreads();

    // ---- t=0 x-part (bias-init C) ----
    bf16x8 xb;
    #pragma unroll
    for (int j = 0; j < 4; ++j) {
        xb[j]     = (__bf16)((const float*)&qA[0][0])[j];
        xb[4 + j] = (__bf16)((const float*)&qA[0][1])[j];
    }
    f32x4 accR  = __builtin_amdgcn_mfma_f32_16x16x32_bf16(aI[0], xb, biasR4, 0, 0, 0);
    f32x4 accZ  = __builtin_amdgcn_mfma_f32_16x16x32_bf16(aI[1], xb, biasZ4, 0, 0, 0);
    f32x4 accXN = __builtin_amdgcn_mfma_f32_16x16x32_bf16(aI[2], xb, biasXN4, 0, 0, 0);

    for (int tc = 0; tc < TSTEPS; tc += 16) {
        #pragma unroll
        for (int s = 0; s < 16; ++s) {
            const int buf = s & 1;  // tc is a multiple of 16

            // post-barrier critical path: h^T fragments
            bf16x8 hb0 = *(const bf16x8*)&hB[buf][l][q * 8];
            bf16x8 hb1 = *(const bf16x8*)&hB[buf][l][32 + q * 8];

            accR = __builtin_amdgcn_mfma_f32_16x16x32_bf16(aH[0][0], hb0, accR, 0, 0, 0);
            accR = __builtin_amdgcn_mfma_f32_16x16x32_bf16(aH[0][1], hb1, accR, 0, 0, 0);
            accZ = __builtin_amdgcn_mfma_f32_16x16x32_bf16(aH[1][0], hb0, accZ, 0, 0, 0);
            accZ = __builtin_amdgcn_mfma_f32_16x16x32_bf16(aH[1][1], hb1, accZ, 0, 0, 0);
            f32x4 accHN = __builtin_amdgcn_mfma_f32_16x16x32_bf16(aH[2][0], hb0, biasHN4, 0, 0, 0);
            accHN = __builtin_amdgcn_mfma_f32_16x16x32_bf16(aH[2][1], hb1, accHN, 0, 0, 0);

            bf16x4 hOut;
            #pragma unroll
            for (int r = 0; r < 4; ++r) {
                // accR/accZ already = -log2e * (pre-activation incl. bias)
                const float rg = __builtin_amdgcn_rcpf(1.0f + __builtin_amdgcn_exp2f(accR[r]));
                const float zg = __builtin_amdgcn_rcpf(1.0f + __builtin_amdgcn_exp2f(accZ[r]));
                const float v  = accXN[r] + rg * accHN[r];
                const float u  = __builtin_amdgcn_exp2f(TWOLOG2E * v);
                const float ng = 1.0f - 2.0f * __builtin_amdgcn_rcpf(1.0f + u);
                h[r] = ng + zg * (h[r] - ng);
                hOut[r] = (__bf16)h[r];
            }
            *(bf16x4*)&hB[buf ^ 1][l][w * 16 + 4 * q] = hOut;

            // burst-refill: chunk tc+16 -> qA at s==7, chunk tc+24 -> qB at s==15.
            // Drained by this step's barrier (once per 8 steps); the other 7
            // barriers have no outstanding vmem so vmcnt(0) is free.
            if (s == 7 && tc + 16 < TSTEPS) {
                #pragma unroll
                for (int u = 0; u < 8; ++u) {
                    const float* p = seqRow + (size_t)(tc + 16 + u) * IDIM;
                    qA[u][0] = *(const float4*)(p);
                    qA[u][1] = *(const float4*)(p + 4);
                }
            }
            if (s == 15 && tc + 24 < TSTEPS) {
                #pragma unroll
                for (int u = 0; u < 8; ++u) {
                    const float* p = seqRow + (size_t)(tc + 24 + u) * IDIM;
                    qB[u][0] = *(const float4*)(p);
                    qB[u][1] = *(const float4*)(p + 4);
                }
            }

            // ---- pre-barrier work for t+1 (h-independent): cvt + x-proj MFMAs ----
            // s+1: slot (s+1)&7 of qA if (s+1)<8 else qB; at s==15 uses qA[0]
            // (already refilled with chunk tc+16 at s==7). Final step computes a
            // dead x-proj for t=512 from stale regs — harmless, results unused.
            {
                const int s1 = s + 1;
                const float* x0 = (s1 < 8) ? (const float*)&qA[s1 & 7][0]
                                           : (s1 < 16) ? (const float*)&qB[s1 & 7][0]
                                                       : (const float*)&qA[0][0];
                const float* x1 = x0 + 4;
                bf16x8 xb1;
                #pragma unroll
                for (int j = 0; j < 4; ++j) {
                    xb1[j]     = (__bf16)x0[j];
                    xb1[4 + j] = (__bf16)x1[j];
                }
                accR  = __builtin_amdgcn_mfma_f32_16x16x32_bf16(aI[0], xb1, biasR4, 0, 0, 0);
                accZ  = __builtin_amdgcn_mfma_f32_16x16x32_bf16(aI[1], xb1, biasZ4, 0, 0, 0);
                accXN = __builtin_amdgcn_mfma_f32_16x16x32_bf16(aI[2], xb1, biasXN4, 0, 0, 0);
            }

            __syncthreads();
        }
    }

    float4 o = {h[0], h[1], h[2], h[3]};
    *(float4*)&out[(size_t)(b0 + l) * HDIM + w * 16 + 4 * q] = o;
}

extern "C" void kernel_launch(void* const* d_in, const int* in_sizes, int n_in,
                              void* d_out, int out_size, void* d_ws, size_t ws_size,
                              hipStream_t stream) {
    const float* seq  = (const float*)d_in[0];
    const float* W_ih = (const float*)d_in[1];
    const float* W_hh = (const float*)d_in[2];
    const float* b_ih = (const float*)d_in[3];
    const float* b_hh = (const float*)d_in[4];
    float* out = (float*)d_out;
    gru_fused_kernel<<<256, 256, 0, stream>>>(seq, W_ih, W_hh, b_ih, b_hh, out);
}